// Round 1
// baseline (450.850 us; speedup 1.0000x reference)
//
#include <hip/hip_runtime.h>
#include <cstdint>

static constexpr int B_DIM = 256;
static constexpr int N_DIM = 65536;
static constexpr int BN = B_DIM * N_DIM;      // 16,777,216 elements per array
static constexpr int VEC = BN / 4;            // float4 count
static constexpr int ROW0_VEC = N_DIM / 4;    // 16,384 float4s in row 0

// Main elementwise AdEx-LIF step. Writes z, v_new, i_new, w_new.
// Row-0 lanes also reduce (max v_before among spiked, first-index tiebreak)
// into a single 64-bit key via wave shuffle + one atomicMax per wave.
__global__ __launch_bounds__(256) void lif_main(
    const float4* __restrict__ x, const float4* __restrict__ v,
    const float4* __restrict__ cur, const float4* __restrict__ w,
    float4* __restrict__ z_out, float4* __restrict__ v_out,
    float4* __restrict__ i_out, float4* __restrict__ w_out,
    unsigned long long* __restrict__ ws_key)
{
    const int t = blockIdx.x * blockDim.x + threadIdx.x;
    if (t >= VEC) return;

    const float4 xv = x[t];
    const float4 vv = v[t];
    const float4 iv = cur[t];
    const float4 wv = w[t];

    float4 zo, vo, io, wo;
    const float* xp = reinterpret_cast<const float*>(&xv);
    const float* vp = reinterpret_cast<const float*>(&vv);
    const float* ip = reinterpret_cast<const float*>(&iv);
    const float* wp = reinterpret_cast<const float*>(&wv);
    float* zq = reinterpret_cast<float*>(&zo);
    float* vq = reinterpret_cast<float*>(&vo);
    float* iq = reinterpret_cast<float*>(&io);
    float* wq = reinterpret_cast<float*>(&wo);

    const bool row0 = (t < ROW0_VEC);   // block-aligned -> wave-uniform
    unsigned long long key = 0ull;

    #pragma unroll
    for (int k = 0; k < 4; ++k) {
        const float X = xp[k];
        const float V = vp[k];
        const float I = ip[k];
        const float W = wp[k];

        const float i_new = I + 0.5f * (X - I);
        const float e     = expf(V - 1.0f);            // DELTA_T=1, V_TH=1
        float v_new       = V + 0.5f * (-V + e + i_new - W);
        const float w_new = 0.5f * W;                  // A=0, tau_adapt_inv=0.5

        const bool spike  = (v_new >= 30.0f);
        const float v_before = v_new;
        if (spike) v_new = 0.0f;                       // V_RESET=0

        zq[k] = spike ? 1.0f : 0.0f;
        vq[k] = v_new;
        iq[k] = i_new;
        wq[k] = w_new;                                 // B_PARAM=0 -> unchanged on spike

        if (row0 && spike) {
            // positive float bits are order-preserving; ~idx -> ties pick min idx
            const unsigned vb  = __float_as_uint(v_before);
            const unsigned idx = (unsigned)(t * 4 + k);
            const unsigned long long cand =
                ((unsigned long long)vb << 32) | (unsigned long long)(~idx);
            key = (cand > key) ? cand : key;
        }
    }

    z_out[t] = zo;
    v_out[t] = vo;
    i_out[t] = io;
    w_out[t] = wo;

    if (row0) {
        #pragma unroll
        for (int off = 32; off > 0; off >>= 1) {
            unsigned long long other = __shfl_down(key, off, 64);
            key = (other > key) ? other : key;
        }
        if ((threadIdx.x & 63) == 0 && key != 0ull) {
            atomicMax(ws_key, key);
        }
    }
}

// Second pass: apply lateral inhibition on row 0 if any spike occurred.
__global__ __launch_bounds__(256) void lif_inhibit(
    float* __restrict__ v_row0, float* __restrict__ w_row0,
    const unsigned long long* __restrict__ ws_key)
{
    const unsigned long long key = *ws_key;
    if (key == 0ull) return;                       // no spike -> no inhibition
    const unsigned winner = ~(unsigned)(key & 0xFFFFFFFFull);
    const int n = blockIdx.x * blockDim.x + threadIdx.x;
    if (n < N_DIM && (unsigned)n != winner) {
        v_row0[n] = -5.0f;                         // INHIBITION
        w_row0[n] = 0.0f;
    }
}

extern "C" void kernel_launch(void* const* d_in, const int* in_sizes, int n_in,
                              void* d_out, int out_size, void* d_ws, size_t ws_size,
                              hipStream_t stream) {
    const float* x   = (const float*)d_in[0];
    const float* v   = (const float*)d_in[1];
    const float* cur = (const float*)d_in[2];
    const float* w   = (const float*)d_in[3];
    float* out = (float*)d_out;

    float* z_out = out;
    float* v_out = out + (size_t)BN;
    float* i_out = out + 2ull * BN;
    float* w_out = out + 3ull * BN;

    unsigned long long* key = (unsigned long long*)d_ws;
    hipMemsetAsync(d_ws, 0, sizeof(unsigned long long), stream);

    lif_main<<<VEC / 256, 256, 0, stream>>>(
        (const float4*)x, (const float4*)v, (const float4*)cur, (const float4*)w,
        (float4*)z_out, (float4*)v_out, (float4*)i_out, (float4*)w_out, key);

    lif_inhibit<<<N_DIM / 256, 256, 0, stream>>>(v_out, w_out, key);
}